// Round 1
// baseline (798.561 us; speedup 1.0000x reference)
//
#include <hip/hip_runtime.h>

// LatentMatrixMemory: M_t = lam*M + (rho*alpha)*(k outer v); r_t = q^T M_t
// B=64, T=2048, DK=DV=128, fp32.
// Parallelization: DV split into NSPLIT slices (columns of M independent);
// grid = (NSPLIT, B) = 256 blocks -> 1 block/CU. M slice lives in registers.

constexpr int B_ = 64, T_ = 2048, DK_ = 128, DV_ = 128;
constexpr int NSPLIT = 4;
constexpr int JS = DV_ / NSPLIT;   // 32 columns per block
constexpr int CT = 32;             // time-chunk staged in LDS

__global__ __launch_bounds__(256, 1) void lmm_scan(
    const float* __restrict__ q_g, const float* __restrict__ k_g,
    const float* __restrict__ v_g, const float* __restrict__ a_g,
    const float* __restrict__ r_g, const float* __restrict__ l_g,
    const float* __restrict__ m0_g, float* __restrict__ out_g)
{
  const int split = blockIdx.x;
  const int b     = blockIdx.y;
  const int tid   = threadIdx.x;
  const int col   = tid >> 3;   // 0..31 : local column j
  const int rg    = tid & 7;    // 0..7  : row-group

  __shared__ float q_s[CT * DK_];
  __shared__ float k_s[CT * DK_];
  __shared__ float v_s[CT * JS];
  __shared__ float w_s[CT];
  __shared__ float l_s[CT];
  __shared__ float o_s[CT * JS];

  const int j = split * JS + col;

  // M slice in registers: element (e,r) covers row i = e*32 + rg*4 + r.
  // This row layout makes the per-step q/k ds_read_b128 conflict-free:
  // 8 rowgroups * 4 banks each = all 32 banks, broadcast across columns.
  float M[4][4];
  #pragma unroll
  for (int e = 0; e < 4; ++e)
    #pragma unroll
    for (int r = 0; r < 4; ++r) {
      int i = e * 32 + rg * 4 + r;
      M[e][r] = m0_g[((size_t)b * DK_ + i) * DV_ + j];
    }

  const float* qb = q_g + (size_t)b * T_ * DK_;
  const float* kb = k_g + (size_t)b * T_ * DK_;
  const float* vb = v_g + (size_t)b * T_ * DV_;
  const float* ab = a_g + (size_t)b * T_;
  const float* rb = r_g + (size_t)b * T_;
  const float* lb = l_g + (size_t)b * T_;
  float*       ob = out_g + (size_t)b * T_ * DV_;

  for (int t0 = 0; t0 < T_; t0 += CT) {
    __syncthreads();   // protect LDS reuse from previous chunk

    // ---- stage q,k chunk: 32x128 floats each, fully coalesced float4 ----
    const float4* qsrc = (const float4*)(qb + (size_t)t0 * DK_);
    const float4* ksrc = (const float4*)(kb + (size_t)t0 * DK_);
    #pragma unroll
    for (int it = 0; it < 4; ++it) {
      int f = it * 256 + tid;
      ((float4*)q_s)[f] = qsrc[f];
      ((float4*)k_s)[f] = ksrc[f];
    }
    // ---- v slice: 32 steps x 32 cols ----
    {
      int s = tid >> 3, c = (tid & 7) * 4;
      *(float4*)(v_s + s * JS + c) =
          *(const float4*)(vb + (size_t)(t0 + s) * DV_ + split * JS + c);
    }
    // ---- scalars: w = rho*alpha, l = lam ----
    if (tid < CT) {
      w_s[tid] = ab[t0 + tid] * rb[t0 + tid];
    } else if (tid < 2 * CT) {
      l_s[tid - CT] = lb[t0 + tid - CT];
    }
    __syncthreads();

    #pragma unroll 4
    for (int s = 0; s < CT; ++s) {
      float w  = w_s[s];
      float l  = l_s[s];
      float wv = w * v_s[s * JS + col];   // (rho*alpha)*v_j
      float accs[4] = {0.f, 0.f, 0.f, 0.f};
      #pragma unroll
      for (int e = 0; e < 4; ++e) {
        float4 qv = *(const float4*)(q_s + s * DK_ + e * 32 + rg * 4);
        float4 kv = *(const float4*)(k_s + s * DK_ + e * 32 + rg * 4);
        M[e][0] = l * M[e][0] + kv.x * wv; accs[e] += qv.x * M[e][0];
        M[e][1] = l * M[e][1] + kv.y * wv; accs[e] += qv.y * M[e][1];
        M[e][2] = l * M[e][2] + kv.z * wv; accs[e] += qv.z * M[e][2];
        M[e][3] = l * M[e][3] + kv.w * wv; accs[e] += qv.w * M[e][3];
      }
      float acc = (accs[0] + accs[1]) + (accs[2] + accs[3]);
      // reduce over the 8 rowgroups (consecutive lanes)
      acc += __shfl_down(acc, 4, 8);
      acc += __shfl_down(acc, 2, 8);
      acc += __shfl_down(acc, 1, 8);
      if (rg == 0) o_s[s * JS + col] = acc;
    }
    __syncthreads();

    // ---- store readouts: 32 steps x 32 cols, coalesced float4 ----
    {
      int s = tid >> 3, c = (tid & 7) * 4;
      *(float4*)(ob + (size_t)(t0 + s) * DV_ + split * JS + c) =
          *(const float4*)(o_s + s * JS + c);
    }
  }
}

extern "C" void kernel_launch(void* const* d_in, const int* in_sizes, int n_in,
                              void* d_out, int out_size, void* d_ws, size_t ws_size,
                              hipStream_t stream) {
  const float* q  = (const float*)d_in[0];
  const float* k  = (const float*)d_in[1];
  const float* v  = (const float*)d_in[2];
  const float* a  = (const float*)d_in[3];
  const float* r  = (const float*)d_in[4];
  const float* l  = (const float*)d_in[5];
  const float* m0 = (const float*)d_in[6];
  float* out = (float*)d_out;

  dim3 grid(NSPLIT, B_);
  lmm_scan<<<grid, 256, 0, stream>>>(q, k, v, a, r, l, m0, out);
}

// Round 2
// 735.210 us; speedup vs baseline: 1.0862x; 1.0862x over previous
//
#include <hip/hip_runtime.h>

// LatentMatrixMemory: M_t = lam*M + (rho*alpha)*(k outer v); r_t = q^T M_t
// B=64, T=2048, DK=DV=128, fp32.
// Round 2: NSPLIT 4->8 (512 blocks = 2 blocks/CU = 2 waves/SIMD) + explicit
// depth-1 register prefetch of LDS operands inside fully-unrolled 32-step
// chunk. Attacks the round-1 latency bound (VALUBusy 21%, occupancy 11.8%).

constexpr int B_ = 64, T_ = 2048, DK_ = 128, DV_ = 128;
constexpr int NSPLIT = 8;
constexpr int JS = DV_ / NSPLIT;   // 16 columns per block
constexpr int CT = 32;             // time-chunk staged in LDS

__global__ __launch_bounds__(256, 2) void lmm_scan(
    const float* __restrict__ q_g, const float* __restrict__ k_g,
    const float* __restrict__ v_g, const float* __restrict__ a_g,
    const float* __restrict__ r_g, const float* __restrict__ l_g,
    const float* __restrict__ m0_g, float* __restrict__ out_g)
{
  const int split = blockIdx.x;
  const int b     = blockIdx.y;
  const int tid   = threadIdx.x;
  const int col   = tid >> 4;   // 0..15 : local column j
  const int rg    = tid & 15;   // 0..15 : row-group

  __shared__ float  q_s[CT * DK_];
  __shared__ float  k_s[CT * DK_];
  __shared__ float  v_s[CT * JS];
  __shared__ float2 wl_s[CT];
  __shared__ float  o_s[CT * JS];

  const int j = split * JS + col;

  // M slice in registers: element (e,r) covers row i = e*64 + rg*4 + r.
  // 16 rowgroups * 16B q/k reads cover all 32 banks twice (2-way = free).
  float M[2][4];
  #pragma unroll
  for (int e = 0; e < 2; ++e)
    #pragma unroll
    for (int r = 0; r < 4; ++r) {
      int i = e * 64 + rg * 4 + r;
      M[e][r] = m0_g[((size_t)b * DK_ + i) * DV_ + j];
    }

  const float* qb = q_g + (size_t)b * T_ * DK_;
  const float* kb = k_g + (size_t)b * T_ * DK_;
  const float* vb = v_g + (size_t)b * T_ * DV_;
  const float* ab = a_g + (size_t)b * T_;
  const float* rb = r_g + (size_t)b * T_;
  const float* lb = l_g + (size_t)b * T_;
  float*       ob = out_g + (size_t)b * T_ * DV_;

  for (int t0 = 0; t0 < T_; t0 += CT) {
    __syncthreads();   // protect LDS reuse from previous chunk

    // ---- stage q,k chunk: 32x128 floats each, fully coalesced float4 ----
    const float4* qsrc = (const float4*)(qb + (size_t)t0 * DK_);
    const float4* ksrc = (const float4*)(kb + (size_t)t0 * DK_);
    #pragma unroll
    for (int it = 0; it < 4; ++it) {
      int f = it * 256 + tid;
      ((float4*)q_s)[f] = qsrc[f];
      ((float4*)k_s)[f] = ksrc[f];
    }
    // ---- v slice: 32 steps x 16 cols (128 float4s) ----
    if (tid < 128) {
      int s = tid >> 2, c = (tid & 3) * 4;
      *(float4*)(v_s + s * JS + c) =
          *(const float4*)(vb + (size_t)(t0 + s) * DV_ + split * JS + c);
    }
    // ---- scalars: w = rho*alpha, l = lam ----
    if (tid < CT) {
      wl_s[tid] = make_float2(ab[t0 + tid] * rb[t0 + tid], lb[t0 + tid]);
    }
    __syncthreads();

    // ---- prefetch step 0 operands into registers ----
    float4 qA0 = *(const float4*)(q_s + 0 * DK_ + 0 * 64 + rg * 4);
    float4 qA1 = *(const float4*)(q_s + 0 * DK_ + 1 * 64 + rg * 4);
    float4 kA0 = *(const float4*)(k_s + 0 * DK_ + 0 * 64 + rg * 4);
    float4 kA1 = *(const float4*)(k_s + 0 * DK_ + 1 * 64 + rg * 4);
    float  vA  = v_s[0 * JS + col];
    float2 wlA = wl_s[0];

    #pragma unroll
    for (int s = 0; s < CT; ++s) {
      // issue next step's LDS loads before using this step's operands
      const int sn = (s + 1 < CT) ? s + 1 : s;
      float4 qB0 = *(const float4*)(q_s + sn * DK_ + 0 * 64 + rg * 4);
      float4 qB1 = *(const float4*)(q_s + sn * DK_ + 1 * 64 + rg * 4);
      float4 kB0 = *(const float4*)(k_s + sn * DK_ + 0 * 64 + rg * 4);
      float4 kB1 = *(const float4*)(k_s + sn * DK_ + 1 * 64 + rg * 4);
      float  vB  = v_s[sn * JS + col];
      float2 wlB = wl_s[sn];

      const float l  = wlA.y;
      const float wv = wlA.x * vA;   // (rho*alpha)*v_j
      float a0 = 0.f, a1 = 0.f;
      M[0][0] = l * M[0][0] + kA0.x * wv; a0 += qA0.x * M[0][0];
      M[0][1] = l * M[0][1] + kA0.y * wv; a0 += qA0.y * M[0][1];
      M[0][2] = l * M[0][2] + kA0.z * wv; a0 += qA0.z * M[0][2];
      M[0][3] = l * M[0][3] + kA0.w * wv; a0 += qA0.w * M[0][3];
      M[1][0] = l * M[1][0] + kA1.x * wv; a1 += qA1.x * M[1][0];
      M[1][1] = l * M[1][1] + kA1.y * wv; a1 += qA1.y * M[1][1];
      M[1][2] = l * M[1][2] + kA1.z * wv; a1 += qA1.z * M[1][2];
      M[1][3] = l * M[1][3] + kA1.w * wv; a1 += qA1.w * M[1][3];

      float acc = a0 + a1;
      // reduce over the 16 rowgroups (consecutive lanes, width-16 groups)
      acc += __shfl_down(acc, 8, 16);
      acc += __shfl_down(acc, 4, 16);
      acc += __shfl_down(acc, 2, 16);
      acc += __shfl_down(acc, 1, 16);
      if (rg == 0) o_s[s * JS + col] = acc;

      // rotate prefetch buffers (resolved by full unroll)
      qA0 = qB0; qA1 = qB1; kA0 = kB0; kA1 = kB1; vA = vB; wlA = wlB;
    }
    __syncthreads();

    // ---- store readouts: 32 steps x 16 cols, float4 ----
    if (tid < 128) {
      int s = tid >> 2, c = (tid & 3) * 4;
      *(float4*)(ob + (size_t)(t0 + s) * DV_ + split * JS + c) =
          *(const float4*)(o_s + s * JS + c);
    }
  }
}

extern "C" void kernel_launch(void* const* d_in, const int* in_sizes, int n_in,
                              void* d_out, int out_size, void* d_ws, size_t ws_size,
                              hipStream_t stream) {
  const float* q  = (const float*)d_in[0];
  const float* k  = (const float*)d_in[1];
  const float* v  = (const float*)d_in[2];
  const float* a  = (const float*)d_in[3];
  const float* r  = (const float*)d_in[4];
  const float* l  = (const float*)d_in[5];
  const float* m0 = (const float*)d_in[6];
  float* out = (float*)d_out;

  dim3 grid(NSPLIT, B_);
  lmm_scan<<<grid, 256, 0, stream>>>(q, k, v, a, r, l, m0, out);
}

// Round 3
// 427.464 us; speedup vs baseline: 1.8681x; 1.7199x over previous
//
#include <hip/hip_runtime.h>
#include <hip/hip_bf16.h>

// LatentMatrixMemory: M_t = lam*M + (rho*alpha)*(k outer v); r_t = q^T M_t
// B=64, T=2048, DK=DV=128, fp32 in/out. Threshold permits bf16 compute.
//
// Round 3: chunkwise linear-attention reformulation on MFMA.
// Per 32-step chunk, with inclusive decay prefix P_t = prod lam (clamped):
//   Vd[s][j] = (rho*alpha)_s / P_s * v[s][j]
//   r_t      = P_t * ( sum_{s<=t} (q_t . k_s) * Vd_s  +  q_t . M )   [GEMM1,2,3]
//   M       <- P_end * ( M + sum_s k_s (x) Vd_s )                    [GEMM4]
// M is the fp32 MFMA accumulator (never quantized as state). Grid: 4 DV-splits
// x 64 batches = 256 blocks; block = 4 waves = (dk 2) x (dv 16-col 2); the
// DK-split partial readouts are summed through LDS (Rbuf).

typedef float  f32x4  __attribute__((ext_vector_type(4)));
typedef short  bf16x8 __attribute__((ext_vector_type(8)));

constexpr int B_ = 64, T_ = 2048;
constexpr int NSPLIT = 4;
constexpr int CT = 32;          // chunk length
constexpr int NCH = T_ / CT;    // 64 chunks

__device__ __forceinline__ bf16x8 cvt8(float4 a, float4 b) {
  union { __hip_bfloat162 h2[4]; bf16x8 v; } u;
  u.h2[0] = __float22bfloat162_rn(make_float2(a.x, a.y));
  u.h2[1] = __float22bfloat162_rn(make_float2(a.z, a.w));
  u.h2[2] = __float22bfloat162_rn(make_float2(b.x, b.y));
  u.h2[3] = __float22bfloat162_rn(make_float2(b.z, b.w));
  return u.v;
}

#define MFMA(a, b, c) __builtin_amdgcn_mfma_f32_16x16x32_bf16((a), (b), (c), 0, 0, 0)

__global__ __launch_bounds__(256) void lmm_mfma(
    const float* __restrict__ q_g, const float* __restrict__ k_g,
    const float* __restrict__ v_g, const float* __restrict__ a_g,
    const float* __restrict__ r_g, const float* __restrict__ l_g,
    const float* __restrict__ m0_g, float* __restrict__ out_g)
{
  const int split = blockIdx.x;
  const int b     = blockIdx.y;
  const int tid   = threadIdx.x;
  const int w     = tid >> 6;        // wave 0..3
  const int lane  = tid & 63;
  const int dk    = w >> 1;          // DK half: rows dk*64 .. +64
  const int dv    = w & 1;           // DV 16-col group within the 32-col split
  const int m     = lane & 15;       // MFMA row/col-in-tile index
  const int quad  = lane >> 4;       // MFMA quad

  // LDS (bf16 unless noted). Row strides are multiples of 8 bf16 (16B) so
  // bf16x8 fragment reads stay 16B-aligned.
  __shared__ __align__(16) __hip_bfloat16 KT [128][40];  // k transposed [i][s]
  __shared__ __align__(16) __hip_bfloat16 VdT[ 32][40];  // Vd transposed [j][s]
  __shared__ __align__(16) __hip_bfloat16 MhT[ 32][136]; // bf16(M) transposed [j][i]
  __shared__ __align__(16) __hip_bfloat16 Sd [4][32][40];// per-wave masked scores [t][s]
  __shared__ float Rbuf[2][32][16];                      // dk=1 partial readouts
  __shared__ float Pt[CT], WP[CT];                       // decay prefix, (rho*a)/P

  const float* qb = q_g + (size_t)b * T_ * 128;
  const float* kb = k_g + (size_t)b * T_ * 128;
  const float* vb = v_g + (size_t)b * T_ * 128;
  const float* ab = a_g + (size_t)b * T_;
  const float* rb = r_g + (size_t)b * T_;
  const float* lb = l_g + (size_t)b * T_;
  float*       ob = out_g + (size_t)b * T_ * 128;

  const int jg = split * 32 + dv * 16 + m;   // this lane's output column

  // M accumulator: 4 tiles along i (rows dk*64+it*16+quad*4+r, col jg), C/D layout.
  f32x4 M[4];
  #pragma unroll
  for (int it = 0; it < 4; ++it)
    #pragma unroll
    for (int r = 0; r < 4; ++r)
      M[it][r] = m0_g[((size_t)b * 128 + dk * 64 + it * 16 + quad * 4 + r) * 128 + jg];

  // staging index precompute
  const int i_kt = tid & 127, shi = tid >> 7;       // KT: i, s-parity
  const int jl_v = tid & 31,  sv0 = tid >> 5;       // VdT: j, s-base

  for (int ch = 0; ch < NCH; ++ch) {
    const int t0 = ch * CT;
    __syncthreads();                                // S0: prev chunk fully done

    // ---- GEMM1 fragment loads straight from global (L2-hot) ----
    bf16x8 Af[2][2], Bf[2][2];
    #pragma unroll
    for (int tb = 0; tb < 2; ++tb)
      #pragma unroll
      for (int ks = 0; ks < 2; ++ks) {
        const float* p = qb + (size_t)(t0 + tb * 16 + m) * 128 + dk * 64 + ks * 32 + quad * 8;
        Af[tb][ks] = cvt8(*(const float4*)p, *(const float4*)(p + 4));
      }
    #pragma unroll
    for (int sb = 0; sb < 2; ++sb)
      #pragma unroll
      for (int ks = 0; ks < 2; ++ks) {
        const float* p = kb + (size_t)(t0 + sb * 16 + m) * 128 + dk * 64 + ks * 32 + quad * 8;
        Bf[sb][ks] = cvt8(*(const float4*)p, *(const float4*)(p + 4));
      }

    // ---- stage KT (raw k, transposed) ----
    #pragma unroll
    for (int rep = 0; rep < 16; ++rep) {
      const int s = rep * 2 + shi;
      KT[i_kt][s] = __float2bfloat16(kb[(size_t)(t0 + s) * 128 + i_kt]);
    }
    // ---- v slice into registers (scaled after WP is ready) ----
    float vreg[4];
    #pragma unroll
    for (int rep = 0; rep < 4; ++rep) {
      const int s = rep * 8 + sv0;
      vreg[rep] = vb[(size_t)(t0 + s) * 128 + split * 32 + jl_v];
    }
    // ---- decay prefix scan (wave 0, lanes 0..31) ----
    if (tid < CT) {
      const float av = ab[t0 + tid], rv = rb[t0 + tid], lv = lb[t0 + tid];
      float P = lv;
      #pragma unroll
      for (int d = 1; d < CT; d <<= 1) {
        const float o = __shfl_up(P, d, CT);
        if (tid >= d) P *= o;
      }
      P = fmaxf(P, 1e-30f);                          // lam==0 reset-safe
      Pt[tid] = P;
      WP[tid] = av * rv / P;
    }
    // ---- publish bf16(M) transposed for GEMM3 (own rows only) ----
    #pragma unroll
    for (int it = 0; it < 4; ++it) {
      union { __hip_bfloat162 h2[2]; uint2 u; } pk;
      pk.h2[0] = __float22bfloat162_rn(make_float2(M[it][0], M[it][1]));
      pk.h2[1] = __float22bfloat162_rn(make_float2(M[it][2], M[it][3]));
      *(uint2*)&MhT[dv * 16 + m][dk * 64 + it * 16 + quad * 4] = pk.u;
    }

    // ---- GEMM1: S[t][s] partial over this dk half ----
    f32x4 S[2][2] = {{{0.f,0.f,0.f,0.f},{0.f,0.f,0.f,0.f}},
                     {{0.f,0.f,0.f,0.f},{0.f,0.f,0.f,0.f}}};
    #pragma unroll
    for (int ks = 0; ks < 2; ++ks)
      #pragma unroll
      for (int tb = 0; tb < 2; ++tb)
        #pragma unroll
        for (int sb = 0; sb < 2; ++sb)
          S[tb][sb] = MFMA(Af[tb][ks], Bf[sb][ks], S[tb][sb]);

    // ---- causal mask, cast, park in private Sd ----
    #pragma unroll
    for (int tb = 0; tb < 2; ++tb)
      #pragma unroll
      for (int sb = 0; sb < 2; ++sb)
        #pragma unroll
        for (int r = 0; r < 4; ++r) {
          const int t_loc = tb * 16 + quad * 4 + r;
          const int s_loc = sb * 16 + m;
          Sd[w][t_loc][s_loc] =
              __float2bfloat16(s_loc <= t_loc ? S[tb][sb][r] : 0.f);
        }

    __syncthreads();                                // S1: WP visible
    // ---- stage VdT = (w/P) * v, transposed ----
    #pragma unroll
    for (int rep = 0; rep < 4; ++rep) {
      const int s = rep * 8 + sv0;
      VdT[jl_v][s] = __float2bfloat16(vreg[rep] * WP[s]);
    }
    __syncthreads();                                // S2: VdT/KT/MhT/Pt visible

    // ---- GEMM2 (intra) + GEMM3 (inter) into R ----
    const bf16x8 VdB = *(const bf16x8*)&VdT[dv * 16 + m][quad * 8];
    f32x4 R[2] = {{0.f,0.f,0.f,0.f},{0.f,0.f,0.f,0.f}};
    #pragma unroll
    for (int tb = 0; tb < 2; ++tb) {
      const bf16x8 sa = *(const bf16x8*)&Sd[w][tb * 16 + m][quad * 8];
      R[tb] = MFMA(sa, VdB, R[tb]);
    }
    #pragma unroll
    for (int ks = 0; ks < 2; ++ks) {
      const bf16x8 mb = *(const bf16x8*)&MhT[dv * 16 + m][dk * 64 + ks * 32 + quad * 8];
      #pragma unroll
      for (int tb = 0; tb < 2; ++tb)
        R[tb] = MFMA(Af[tb][ks], mb, R[tb]);
    }
    // dk=1 waves publish partials
    if (dk == 1) {
      #pragma unroll
      for (int tb = 0; tb < 2; ++tb)
        #pragma unroll
        for (int r = 0; r < 4; ++r)
          Rbuf[dv][tb * 16 + quad * 4 + r][m] = R[tb][r];
    }

    // ---- GEMM4: M += K^T Vd, then decay by P_end ----
    #pragma unroll
    for (int it = 0; it < 4; ++it) {
      const bf16x8 ka = *(const bf16x8*)&KT[dk * 64 + it * 16 + m][quad * 8];
      M[it] = MFMA(ka, VdB, M[it]);
    }
    const float Pend = Pt[CT - 1];
    #pragma unroll
    for (int it = 0; it < 4; ++it)
      #pragma unroll
      for (int r = 0; r < 4; ++r)
        M[it][r] *= Pend;

    __syncthreads();                                // S3: Rbuf visible
    // ---- dk=0 waves: combine halves, scale by P_t, store out ----
    if (dk == 0) {
      #pragma unroll
      for (int tb = 0; tb < 2; ++tb)
        #pragma unroll
        for (int r = 0; r < 4; ++r) {
          const int t_loc = tb * 16 + quad * 4 + r;
          const float tot = R[tb][r] + Rbuf[dv][t_loc][m];
          ob[(size_t)(t0 + t_loc) * 128 + jg] = Pt[t_loc] * tot;
        }
    }
  }
}

extern "C" void kernel_launch(void* const* d_in, const int* in_sizes, int n_in,
                              void* d_out, int out_size, void* d_ws, size_t ws_size,
                              hipStream_t stream) {
  const float* q  = (const float*)d_in[0];
  const float* k  = (const float*)d_in[1];
  const float* v  = (const float*)d_in[2];
  const float* a  = (const float*)d_in[3];
  const float* r  = (const float*)d_in[4];
  const float* l  = (const float*)d_in[5];
  const float* m0 = (const float*)d_in[6];
  float* out = (float*)d_out;

  dim3 grid(NSPLIT, B_);
  lmm_mfma<<<grid, 256, 0, stream>>>(q, k, v, a, r, l, m0, out);
}